// Round 9
// baseline (2323.801 us; speedup 1.0000x reference)
//
#include <hip/hip_runtime.h>
#include <math.h>

typedef __attribute__((ext_vector_type(4))) float f32x4;
typedef __attribute__((ext_vector_type(8))) short short8;
typedef __attribute__((ext_vector_type(4))) unsigned int u32x4;
typedef unsigned short ushort_t;
typedef unsigned int uint_t;

// ---------------- workspace layout (float offsets) ----------------
// Encoder: Ah [32*64*16900]u16 @0, Al @17305600f; Bh [32*128*4356]u16 @B_OFF, Bl @B_OFF+8921088f
// Middle (A dead): C f32 @0 (9469952f), Dq f32 @9469952, E @18939904, Q @21037056
// Decoder: Cb16 u16 @0 (4734976f), Bb16 u16 @B_OFF (8921088f), A16 u16 @0 (17305600f)
static const size_t AL_OFF     = 17305600;
static const size_t C_OFF      = 0;
static const size_t D_OFF      = 9469952;
static const size_t E_OFF      = 18939904;
static const size_t Q_OFF      = 21037056;
static const size_t B_OFF      = 34611200;
static const size_t BL_OFF     = 34611200 + 8921088;
static const size_t CBT_OFF    = 52453376;  // 64*1024
static const size_t CNORM_OFF  = 52518912;  // 1024
static const size_t COUNTS_OFF = 52519936;  // 1024
static const size_t SUMSQ_OFF  = 52520960;  // 1 (+3)
static const size_t WT_OFF     = 52520964;

__device__ __forceinline__ ushort_t f2b(float f) {
  uint_t u = __float_as_uint(f);
  uint_t r = (u + 0x7FFFu + ((u >> 16) & 1u)) >> 16;
  return (ushort_t)r;
}
__device__ __forceinline__ float b2f(ushort_t h) {
  return __uint_as_float(((uint_t)h) << 16);
}

// ---------------- weight prep ----------------
__global__ void k_wt_conv(const float* __restrict__ w, float* __restrict__ wT,
                          int Cin, int Cout, int K) {
  const int n = Cin * Cout * K;
  for (int i = blockIdx.x * 256 + threadIdx.x; i < n; i += gridDim.x * 256) {
    const int co = i % Cout;
    const int k  = (i / Cout) % K;
    const int ci = i / (Cout * K);
    wT[i] = w[((size_t)co * Cin + ci) * K + k];
  }
}
__global__ void k_wtb(const float* __restrict__ w, ushort_t* __restrict__ wbT,
                      int Cin, int Cout) {
  const int n = 4 * Cout * Cin * 4;
  for (int i = blockIdx.x * 256 + threadIdx.x; i < n; i += gridDim.x * 256) {
    const int tap = i & 3;
    const int ci  = (i >> 2) % Cin;
    const int co  = ((i >> 2) / Cin) % Cout;
    const int ph  = (i >> 2) / (Cin * Cout);
    const int ey = ph >> 1, ex = ph & 1;
    const int ty = tap >> 1, tx = tap & 1;
    const int kidx = (3 - 2 * ty - ey) * 4 + (3 - 2 * tx - ex);
    wbT[i] = f2b(w[((size_t)ci * Cout + co) * 16 + kidx]);
  }
}
__global__ void k_wsplit(const float* __restrict__ w, ushort_t* __restrict__ wh,
                         ushort_t* __restrict__ wl, int n) {
  for (int i = blockIdx.x * 256 + threadIdx.x; i < n; i += gridDim.x * 256) {
    const float v = w[i];
    const ushort_t h = f2b(v);
    wh[i] = h;
    wl[i] = f2b(v - b2f(h));
  }
}
__global__ void k_cbt(const float* __restrict__ cb, float* __restrict__ cbT,
                      float* __restrict__ cnorm) {
  const int c = blockIdx.x * 256 + threadIdx.x;
  float s = 0.0f;
  for (int ci = 0; ci < 64; ++ci) {
    const float v = cb[(size_t)c * 64 + ci];
    s += v * v;
    cbT[(size_t)ci * 1024 + c] = v;
  }
  cnorm[c] = s;
}

// ---------------- enc0: conv 4x4 s2 p1, Cin=3, staged; writes SPLIT u16 planes ----------
__global__ __launch_bounds__(256) void k_conv4s2_s3(
    const float* __restrict__ in, const float* __restrict__ wT,
    const float* __restrict__ bias, ushort_t* __restrict__ oh,
    ushort_t* __restrict__ ol) {
  const int b   = blockIdx.z;
  const int co0 = blockIdx.y << 4;
  const int oy0 = (blockIdx.x >> 2) << 5;
  const int ox0 = (blockIdx.x & 3) << 5;
  const int tid = threadIdx.x;
  const int ty = tid >> 4, tx = tid & 15;
  __shared__ float tin[3][66][67];
  float acc[4][16];
#pragma unroll
  for (int p = 0; p < 4; ++p)
#pragma unroll
    for (int co = 0; co < 16; ++co) acc[p][co] = 0.0f;

  const int iy0 = (oy0 << 1) - 1, ix0 = (ox0 << 1) - 1;
  for (int c = 0; c < 3; ++c) {
    const float* ip = in + (size_t)(b * 3 + c) * 65536;
    for (int j = tid; j < 66 * 66; j += 256) {
      const int r = j / 66, col = j - r * 66;
      const int iy = iy0 + r, ix = ix0 + col;
      float v = 0.0f;
      if ((unsigned)iy < 256u && (unsigned)ix < 256u) v = ip[iy * 256 + ix];
      tin[c][r][col] = v;
    }
  }
  __syncthreads();
#pragma unroll
  for (int c = 0; c < 3; ++c) {
    const float* wp = wT + (size_t)c * 16 * 64 + co0;
#pragma unroll
    for (int ky = 0; ky < 4; ++ky)
#pragma unroll
      for (int kx = 0; kx < 4; ++kx) {
        const float v0 = tin[c][2 * ty + ky][2 * tx + kx];
        const float v1 = tin[c][2 * ty + ky][2 * tx + 32 + kx];
        const float v2 = tin[c][2 * ty + 32 + ky][2 * tx + kx];
        const float v3 = tin[c][2 * ty + 32 + ky][2 * tx + 32 + kx];
        const float* wk = wp + (ky * 4 + kx) * 64;
#pragma unroll
        for (int co = 0; co < 16; ++co) {
          const float wv = wk[co];
          acc[0][co] = fmaf(v0, wv, acc[0][co]);
          acc[1][co] = fmaf(v1, wv, acc[1][co]);
          acc[2][co] = fmaf(v2, wv, acc[2][co]);
          acc[3][co] = fmaf(v3, wv, acc[3][co]);
        }
      }
  }
#pragma unroll
  for (int co = 0; co < 16; ++co) {
    const float bv = bias[co0 + co];
    ushort_t* oph = oh + (size_t)(b * 64 + co0 + co) * 16900;
    ushort_t* opl = ol + (size_t)(b * 64 + co0 + co) * 16900;
    const int idx[4] = {(oy0 + ty + 1) * 130 + ox0 + tx + 1,
                        (oy0 + ty + 1) * 130 + ox0 + tx + 17,
                        (oy0 + ty + 17) * 130 + ox0 + tx + 1,
                        (oy0 + ty + 17) * 130 + ox0 + tx + 17};
#pragma unroll
    for (int p = 0; p < 4; ++p) {
      const float v = fmaxf(acc[p][co] + bv, 0.0f);
      const ushort_t h = f2b(v);
      oph[idx[p]] = h;
      opl[idx[p]] = f2b(v - b2f(h));
    }
  }
}

// ---------------- split-bf16 MFMA conv 4x4 s2 p1 (encoder), pre-split u16 planes -----------
// K-pair = 64 per barrier (2 chunks of 32), 24 MFMAs/pair. OUT_SPLIT: 1 -> u16 hi/lo planes.
template <int WSHIFT, int CIN, int COUT, int WP, int INSTRIDE, int WOP, int OUTSTRIDE,
          int OUT_SPLIT>
__global__ __launch_bounds__(256) void k_conv4s2_mfma(
    const ushort_t* __restrict__ inh, const ushort_t* __restrict__ inl,
    const ushort_t* __restrict__ wbh, const ushort_t* __restrict__ wbl,
    const float* __restrict__ bias, float* __restrict__ outf,
    ushort_t* __restrict__ oth, ushort_t* __restrict__ otl) {
  constexpr int W = 1 << WSHIFT;
  constexpr int NPAIR = CIN / 4;
  __shared__ __align__(16) short lsAh[2][64 * 40];
  __shared__ __align__(16) short lsAl[2][64 * 40];
  __shared__ __align__(16) short lsBh[2][64 * 40];
  __shared__ __align__(16) short lsBl[2][64 * 40];

  const int tid = threadIdx.x;
  const int b = blockIdx.z;
  const int co_b0 = blockIdx.y << 6;
  const int pxb0 = blockIdx.x << 6;
  const int spx = tid & 63;
  const int kg  = tid >> 6;
  const int sy = (pxb0 + spx) >> WSHIFT;
  const int sx = (pxb0 + spx) & (W - 1);
  const size_t aoff = (size_t)(b * CIN + (kg >> 1)) * INSTRIDE
                    + (size_t)(2 * sy + 2 * (kg & 1)) * WP + 2 * sx;
  const ushort_t* iph0 = inh + aoff;
  const ushort_t* ipl0 = inl + aoff;
  const ushort_t* wbase_h = wbh + (size_t)(co_b0 + spx) * (CIN * 16) + kg * 8;
  const ushort_t* wbase_l = wbl + (size_t)(co_b0 + spx) * (CIN * 16) + kg * 8;

  const int lane = tid & 63, wid = tid >> 6;
  const int wm = wid & 1, wn = wid >> 1;
  const int arow = lane & 15, ag = lane >> 4;

  f32x4 acc[2][2];
#pragma unroll
  for (int m = 0; m < 2; ++m)
#pragma unroll
    for (int n = 0; n < 2; ++n) acc[m][n] = (f32x4){0.f, 0.f, 0.f, 0.f};

  uint_t ah_[2][4], al_[2][4];
  u32x4 bh_[2], bl_[2];
  auto loadpair = [&](int pr) {
#pragma unroll
    for (int c = 0; c < 2; ++c) {
      const int ch = 2 * pr + c;
      const ushort_t* ph = iph0 + (size_t)(2 * ch) * INSTRIDE;
      const ushort_t* pl = ipl0 + (size_t)(2 * ch) * INSTRIDE;
      ah_[c][0] = *(const uint_t*)(ph);      ah_[c][1] = *(const uint_t*)(ph + 2);
      ah_[c][2] = *(const uint_t*)(ph + WP); ah_[c][3] = *(const uint_t*)(ph + WP + 2);
      al_[c][0] = *(const uint_t*)(pl);      al_[c][1] = *(const uint_t*)(pl + 2);
      al_[c][2] = *(const uint_t*)(pl + WP); al_[c][3] = *(const uint_t*)(pl + WP + 2);
      bh_[c] = *(const u32x4*)(wbase_h + (size_t)ch * 32);
      bl_[c] = *(const u32x4*)(wbase_l + (size_t)ch * 32);
    }
  };

  loadpair(0);
  for (int pr = 0; pr < NPAIR; ++pr) {
    __syncthreads();
#pragma unroll
    for (int c = 0; c < 2; ++c) {
      *(u32x4*)(&lsAh[c][spx * 40 + kg * 8]) = (u32x4){ah_[c][0], ah_[c][1], ah_[c][2], ah_[c][3]};
      *(u32x4*)(&lsAl[c][spx * 40 + kg * 8]) = (u32x4){al_[c][0], al_[c][1], al_[c][2], al_[c][3]};
      *(u32x4*)(&lsBh[c][spx * 40 + kg * 8]) = bh_[c];
      *(u32x4*)(&lsBl[c][spx * 40 + kg * 8]) = bl_[c];
    }
    if (pr + 1 < NPAIR) loadpair(pr + 1);
    __syncthreads();
#pragma unroll
    for (int c = 0; c < 2; ++c) {
      short8 ah[2], al[2], bh[2], bl[2];
#pragma unroll
      for (int m = 0; m < 2; ++m) {
        ah[m] = *(const short8*)(&lsAh[c][(wm * 32 + m * 16 + arow) * 40 + ag * 8]);
        al[m] = *(const short8*)(&lsAl[c][(wm * 32 + m * 16 + arow) * 40 + ag * 8]);
      }
#pragma unroll
      for (int n = 0; n < 2; ++n) {
        bh[n] = *(const short8*)(&lsBh[c][(wn * 32 + n * 16 + arow) * 40 + ag * 8]);
        bl[n] = *(const short8*)(&lsBl[c][(wn * 32 + n * 16 + arow) * 40 + ag * 8]);
      }
#pragma unroll
      for (int m = 0; m < 2; ++m)
#pragma unroll
        for (int n = 0; n < 2; ++n) {
          acc[m][n] = __builtin_amdgcn_mfma_f32_16x16x32_bf16(ah[m], bh[n], acc[m][n], 0, 0, 0);
          acc[m][n] = __builtin_amdgcn_mfma_f32_16x16x32_bf16(ah[m], bl[n], acc[m][n], 0, 0, 0);
          acc[m][n] = __builtin_amdgcn_mfma_f32_16x16x32_bf16(al[m], bh[n], acc[m][n], 0, 0, 0);
        }
    }
  }

#pragma unroll
  for (int m = 0; m < 2; ++m)
#pragma unroll
    for (int n = 0; n < 2; ++n) {
      const int col = co_b0 + wn * 32 + n * 16 + arow;
      const float bv = bias[col];
#pragma unroll
      for (int r = 0; r < 4; ++r) {
        const int pxl = pxb0 + wm * 32 + m * 16 + ag * 4 + r;
        const int yy = pxl >> WSHIFT, xx = pxl & (W - 1);
        const float v = fmaxf(acc[m][n][r] + bv, 0.0f);
        if constexpr (OUT_SPLIT) {
          const size_t o = (size_t)(b * COUT + col) * OUTSTRIDE + (size_t)(yy + 1) * WOP + xx + 1;
          const ushort_t h = f2b(v);
          oth[o] = h;
          otl[o] = f2b(v - b2f(h));
        } else {
          outf[(size_t)(b * COUT + col) * OUTSTRIDE + (size_t)(yy + 1) * WOP + xx + 1] = v;
        }
      }
    }
}

// ---------------- conv3x3 p1 (256->64 @32x32), px-parallel (fp32) ----------
__global__ __launch_bounds__(256) void k_conv3x3_px(
    const float* __restrict__ in, const float* __restrict__ wT,
    const float* __restrict__ bias, float* __restrict__ out) {
  const int b   = blockIdx.z;
  const int co0 = blockIdx.y << 4;
  const int px  = blockIdx.x * 256 + threadIdx.x;
  const int y = px >> 5, x = px & 31;
  const float* ip = in + (size_t)b * 256 * 1156 + (size_t)y * 34 + x;
  float acc[16];
#pragma unroll
  for (int co = 0; co < 16; ++co) acc[co] = 0.0f;
  const float* wp = wT + co0;
  for (int ci = 0; ci < 256; ++ci) {
    float v[9];
#pragma unroll
    for (int dy = 0; dy < 3; ++dy)
#pragma unroll
      for (int dx = 0; dx < 3; ++dx) v[dy * 3 + dx] = fmaxf(ip[dy * 34 + dx], 0.0f);
    ip += 1156;
    const float* wk = wp;
#pragma unroll
    for (int t = 0; t < 9; ++t) {
      const float vv = v[t];
#pragma unroll
      for (int co = 0; co < 16; ++co) acc[co] = fmaf(vv, wk[co], acc[co]);
      wk += 64;
    }
    wp += 9 * 64;
  }
  float* op = out + (size_t)(b * 64 + co0) * 1024 + px;
#pragma unroll
  for (int co = 0; co < 16; ++co) op[(size_t)co * 1024] = acc[co] + bias[co0 + co];
}

// ---------------- conv1x1 px-parallel; OUT_BF16 writes u16 plane ----------
template <int IN_RELU, int HAS_RES, int IN_PAD, int OUT_PAD, int OUT_BF16>
__global__ __launch_bounds__(256) void k_conv1x1_px(
    const float* __restrict__ in, const float* __restrict__ wT,
    const float* __restrict__ bias, const float* __restrict__ res,
    float* __restrict__ out, int Cin, int Cout) {
  const int b   = blockIdx.z;
  const int co0 = blockIdx.y << 4;
  const int px  = blockIdx.x * 256 + threadIdx.x;
  const int ppad = 35 + px + 2 * (px >> 5);
  const int ioff = IN_PAD ? ppad : px;
  const int istr = IN_PAD ? 1156 : 1024;
  const int ooff = OUT_PAD ? ppad : px;
  const int ostr = OUT_PAD ? 1156 : 1024;
  float acc[16];
#pragma unroll
  for (int co = 0; co < 16; ++co) acc[co] = 0.0f;
  const float* ip = in + (size_t)b * Cin * istr + ioff;
  const float* wp = wT + co0;
  for (int ci = 0; ci < Cin; ++ci) {
    float v = *ip;
    if (IN_RELU) v = fmaxf(v, 0.0f);
    ip += istr;
#pragma unroll
    for (int co = 0; co < 16; ++co) acc[co] = fmaf(v, wp[co], acc[co]);
    wp += Cout;
  }
  const float* rp = res + (size_t)(b * Cout + co0) * ostr + ooff;
#pragma unroll
  for (int co = 0; co < 16; ++co) {
    float r = acc[co] + bias[co0 + co];
    if (HAS_RES) r += rp[(size_t)co * ostr];
    if constexpr (OUT_BF16) {
      ushort_t* ob = ((ushort_t*)out) + (size_t)(b * Cout + co0) * ostr + ooff;
      ob[(size_t)co * ostr] = f2b(r);
    } else {
      float* op = out + (size_t)(b * Cout + co0) * ostr + ooff;
      op[(size_t)co * ostr] = r;
    }
  }
}

// ---------------- MFMA bf16 tconv; u16-plane in; GRP chunks (K=32*GRP) per barrier ---------
// OUTMODE: 0 = u16 bf16 padded plane (relu), 1 = FINAL fused 1x1 -> fp32 d_out
template <int PXB, int COB, int WSHIFT, int CIN, int COUT, int WP, int INSTRIDE,
          int WOP, int OUTSTRIDE, int OUTMODE, int GRP>
__global__ __launch_bounds__(256) void k_tconv_mfma(
    const ushort_t* __restrict__ in, const ushort_t* __restrict__ wbT,
    const float* __restrict__ bias, const float* __restrict__ ow,
    const float* __restrict__ ob, ushort_t* __restrict__ outp,
    float* __restrict__ outf) {
  constexpr int W = 1 << WSHIFT;
  constexpr int NCH = CIN / 8;
  constexpr int NGRP = NCH / GRP;
  constexpr int PXSH = (PXB == 64) ? 6 : 7;
  constexpr int COSH = (COB == 64) ? 6 : 5;
  constexpr int NKG = (PXB * 4) / 256;
  constexpr int KGSTEP = 256 / PXB;
  __shared__ __align__(16) short lsA[GRP][PXB * 40];
  __shared__ __align__(16) short lsB[GRP][COB * 40];
  __shared__ float pxco[OUTMODE ? PXB : 1][33];

  const int tid = threadIdx.x;
  const int b = blockIdx.z;
  const int phase = blockIdx.y & 3;
  const int ey = phase >> 1, ex = phase & 1;
  const int co_b0 = (blockIdx.y >> 2) * COB;
  const int pxb0 = blockIdx.x * PXB;

  const int spx = tid & (PXB - 1);
  const int kg0 = tid >> PXSH;
  const int sy = (pxb0 + spx) >> WSHIFT;
  const int sx = (pxb0 + spx) & (W - 1);
  const ushort_t* ipa = in + (size_t)(b * CIN) * INSTRIDE + (size_t)(sy + ey) * WP + (sx + ex);
  const int sco = tid & (COB - 1);
  const int skg = tid >> COSH;
  const bool bstage = (tid < COB * 4);
  const ushort_t* wrow = wbT + ((size_t)(phase * COUT + co_b0 + sco) * CIN) * 4;

  const int lane = tid & 63, wid = tid >> 6;
  const int wm = wid % (PXB / 32), wn = wid / (PXB / 32);
  const int arow = lane & 15, ag = lane >> 4;

  f32x4 acc[2][2];
#pragma unroll
  for (int m = 0; m < 2; ++m)
#pragma unroll
    for (int n = 0; n < 2; ++n) acc[m][n] = (f32x4){0.f, 0.f, 0.f, 0.f};

  uint_t ga[GRP][NKG][4];
  u32x4 gb[GRP];
  auto pk2 = [](ushort_t a, ushort_t c) { return (uint_t)a | ((uint_t)c << 16); };
  auto loadgrp = [&](int g) {
#pragma unroll
    for (int c = 0; c < GRP; ++c) {
      const int ch = g * GRP + c;
#pragma unroll
      for (int k = 0; k < NKG; ++k) {
        const ushort_t* p = ipa + (size_t)(ch * 8 + (kg0 + k * KGSTEP) * 2) * INSTRIDE;
        const ushort_t* q = p + INSTRIDE;
        ga[c][k][0] = pk2(p[0], p[1]);
        ga[c][k][1] = pk2(p[WP], p[WP + 1]);
        ga[c][k][2] = pk2(q[0], q[1]);
        ga[c][k][3] = pk2(q[WP], q[WP + 1]);
      }
      if (bstage) gb[c] = *(const u32x4*)(wrow + (size_t)ch * 32 + skg * 8);
    }
  };

  loadgrp(0);
  for (int g = 0; g < NGRP; ++g) {
    __syncthreads();
#pragma unroll
    for (int c = 0; c < GRP; ++c) {
#pragma unroll
      for (int k = 0; k < NKG; ++k)
        *(u32x4*)(&lsA[c][spx * 40 + (kg0 + k * KGSTEP) * 8]) =
            (u32x4){ga[c][k][0], ga[c][k][1], ga[c][k][2], ga[c][k][3]};
      if (bstage) *(u32x4*)(&lsB[c][sco * 40 + skg * 8]) = gb[c];
    }
    if (g + 1 < NGRP) loadgrp(g + 1);
    __syncthreads();
#pragma unroll
    for (int c = 0; c < GRP; ++c) {
      const short8 a0 = *(const short8*)(&lsA[c][(wm * 32 + arow) * 40 + ag * 8]);
      const short8 a1 = *(const short8*)(&lsA[c][(wm * 32 + 16 + arow) * 40 + ag * 8]);
      const short8 b0 = *(const short8*)(&lsB[c][(wn * 32 + arow) * 40 + ag * 8]);
      const short8 b1 = *(const short8*)(&lsB[c][(wn * 32 + 16 + arow) * 40 + ag * 8]);
      acc[0][0] = __builtin_amdgcn_mfma_f32_16x16x32_bf16(a0, b0, acc[0][0], 0, 0, 0);
      acc[0][1] = __builtin_amdgcn_mfma_f32_16x16x32_bf16(a0, b1, acc[0][1], 0, 0, 0);
      acc[1][0] = __builtin_amdgcn_mfma_f32_16x16x32_bf16(a1, b0, acc[1][0], 0, 0, 0);
      acc[1][1] = __builtin_amdgcn_mfma_f32_16x16x32_bf16(a1, b1, acc[1][1], 0, 0, 0);
    }
  }

  if constexpr (!OUTMODE) {
#pragma unroll
    for (int m = 0; m < 2; ++m)
#pragma unroll
      for (int n = 0; n < 2; ++n) {
        const int col = co_b0 + wn * 32 + n * 16 + arow;
        const float bv = bias[col];
        ushort_t* obase = outp + (size_t)(b * COUT + col) * OUTSTRIDE;
#pragma unroll
        for (int r = 0; r < 4; ++r) {
          const int pxl = pxb0 + wm * 32 + m * 16 + ag * 4 + r;
          const int yy = pxl >> WSHIFT, xx = pxl & (W - 1);
          obase[(size_t)(2 * yy + ey + 1) * WOP + (2 * xx + ex + 1)] =
              f2b(fmaxf(acc[m][n][r] + bv, 0.0f));
        }
      }
  } else {
#pragma unroll
    for (int m = 0; m < 2; ++m)
#pragma unroll
      for (int n = 0; n < 2; ++n) {
        const int col = wn * 32 + n * 16 + arow;
        const float bv = bias[col];
#pragma unroll
        for (int r = 0; r < 4; ++r) {
          const int pxl = wm * 32 + m * 16 + ag * 4 + r;
          pxco[pxl][col] = fmaxf(acc[m][n][r] + bv, 0.0f);
        }
      }
    __syncthreads();
    if (tid < PXB) {
      const int pxg = pxb0 + tid;
      const int yy = pxg >> WSHIFT, xx = pxg & (W - 1);
      const int oy = 2 * yy + ey, ox = 2 * xx + ex;
      float o0 = ob[0], o1 = ob[1], o2 = ob[2];
#pragma unroll
      for (int co = 0; co < 32; ++co) {
        const float v = pxco[tid][co];
        o0 = fmaf(ow[co], v, o0);
        o1 = fmaf(ow[32 + co], v, o1);
        o2 = fmaf(ow[64 + co], v, o2);
      }
      outf[((size_t)(b * 3 + 0) * 256 + oy) * 256 + ox] = o0;
      outf[((size_t)(b * 3 + 1) * 256 + oy) * 256 + ox] = o1;
      outf[((size_t)(b * 3 + 2) * 256 + oy) * 256 + ox] = o2;
    }
  }
}

// ---------------- VQ (fp32 exact) ----------------
__global__ __launch_bounds__(256) void k_vq(
    const float* __restrict__ zlat, const float* __restrict__ cbT,
    const float* __restrict__ cnorm, const float* __restrict__ cb,
    float* __restrict__ q, float* __restrict__ counts, float* __restrict__ sumsq) {
  const int tid = threadIdx.x;
  const int px0 = blockIdx.x << 4;
  const int b   = px0 >> 10;
  const int pl0 = px0 & 1023;
  __shared__ float zT[64][17];
  __shared__ float rd[16][256];
  __shared__ int   ri[16][256];
  for (int j = tid; j < 1024; j += 256) {
    const int ci = j >> 4, p = j & 15;
    zT[ci][p] = zlat[(size_t)(b * 64 + ci) * 1024 + pl0 + p];
  }
  __syncthreads();
  float dot[4][16];
#pragma unroll
  for (int k = 0; k < 4; ++k)
#pragma unroll
    for (int p = 0; p < 16; ++p) dot[k][p] = 0.0f;
  for (int ci = 0; ci < 64; ++ci) {
    float z[16];
#pragma unroll
    for (int p = 0; p < 16; ++p) z[p] = zT[ci][p];
#pragma unroll
    for (int k = 0; k < 4; ++k) {
      const float cv = cbT[(size_t)ci * 1024 + (k << 8) + tid];
#pragma unroll
      for (int p = 0; p < 16; ++p) dot[k][p] = fmaf(cv, z[p], dot[k][p]);
    }
  }
  float bd[16]; int bi[16];
#pragma unroll
  for (int p = 0; p < 16; ++p) { bd[p] = 3.4e38f; bi[p] = 0; }
#pragma unroll
  for (int k = 0; k < 4; ++k) {
    const int c = (k << 8) + tid;
    const float cn = cnorm[c];
#pragma unroll
    for (int p = 0; p < 16; ++p) {
      const float d = cn - 2.0f * dot[k][p];
      if (d < bd[p]) { bd[p] = d; bi[p] = c; }
    }
  }
#pragma unroll
  for (int p = 0; p < 16; ++p) { rd[p][tid] = bd[p]; ri[p][tid] = bi[p]; }
  __syncthreads();
  for (int s = 128; s >= 1; s >>= 1) {
    if (tid < s) {
#pragma unroll
      for (int p = 0; p < 16; ++p) {
        const float d2 = rd[p][tid + s]; const int i2 = ri[p][tid + s];
        const float d1 = rd[p][tid];     const int i1 = ri[p][tid];
        if (d2 < d1 || (d2 == d1 && i2 < i1)) { rd[p][tid] = d2; ri[p][tid] = i2; }
      }
    }
    __syncthreads();
  }
  if (tid < 16) atomicAdd(&counts[ri[tid][0]], 1.0f);
  const int p    = tid >> 4;
  const int best = ri[p][0];
  const int cb0  = (tid & 15) << 2;
  float ss = 0.0f;
  float* qp = q + (size_t)b * 65536 + pl0 + p;
#pragma unroll
  for (int cc = 0; cc < 4; ++cc) {
    const int ci = cb0 + cc;
    const float qv = cb[(size_t)best * 64 + ci];
    const float zv = zT[ci][p];
    const float df = qv - zv;
    ss += df * df;
    qp[(size_t)ci * 1024] = qv;
  }
#pragma unroll
  for (int o = 32; o > 0; o >>= 1) ss += __shfl_down(ss, o);
  if ((tid & 63) == 0) atomicAdd(sumsq, ss);
}

__global__ void k_final(const float* __restrict__ counts, const float* __restrict__ sumsq,
                        float* __restrict__ out2) {
  const int tid = threadIdx.x;
  float h = 0.0f;
  for (int k = tid; k < 1024; k += 256) {
    const float pr = counts[k] * (1.0f / 32768.0f);
    h -= pr * logf(pr + 1e-10f);
  }
#pragma unroll
  for (int o = 32; o > 0; o >>= 1) h += __shfl_down(h, o);
  __shared__ float hs[4];
  if ((tid & 63) == 0) hs[tid >> 6] = h;
  __syncthreads();
  if (tid == 0) {
    out2[0] = 1.25f * sumsq[0] * (1.0f / 2097152.0f);
    out2[1] = expf(hs[0] + hs[1] + hs[2] + hs[3]);
  }
}

// ---------------- launcher ----------------
extern "C" void kernel_launch(void* const* d_in, const int* in_sizes, int n_in,
                              void* d_out, int out_size, void* d_ws, size_t ws_size,
                              hipStream_t stream) {
  const float* x        = (const float*)d_in[0];
  const float* enc_w0   = (const float*)d_in[1];
  const float* enc_b0   = (const float*)d_in[2];
  const float* enc_w1   = (const float*)d_in[3];
  const float* enc_b1   = (const float*)d_in[4];
  const float* enc_w2   = (const float*)d_in[5];
  const float* enc_b2   = (const float*)d_in[6];
  const float* er0w1    = (const float*)d_in[7];
  const float* er0b1    = (const float*)d_in[8];
  const float* er0w2    = (const float*)d_in[9];
  const float* er0b2    = (const float*)d_in[10];
  const float* er1w1    = (const float*)d_in[11];
  const float* er1b1    = (const float*)d_in[12];
  const float* er1w2    = (const float*)d_in[13];
  const float* er1b2    = (const float*)d_in[14];
  const float* eadj_w   = (const float*)d_in[15];
  const float* eadj_b   = (const float*)d_in[16];
  const float* codebook = (const float*)d_in[17];
  const float* dadj_w   = (const float*)d_in[18];
  const float* dadj_b   = (const float*)d_in[19];
  const float* dr0w1    = (const float*)d_in[20];
  const float* dr0b1    = (const float*)d_in[21];
  const float* dr0w2    = (const float*)d_in[22];
  const float* dr0b2    = (const float*)d_in[23];
  const float* dr1w1    = (const float*)d_in[24];
  const float* dr1b1    = (const float*)d_in[25];
  const float* dr1w2    = (const float*)d_in[26];
  const float* dr1b2    = (const float*)d_in[27];
  const float* tw0      = (const float*)d_in[28];
  const float* tb0      = (const float*)d_in[29];
  const float* tw1      = (const float*)d_in[30];
  const float* tb1      = (const float*)d_in[31];
  const float* tw2      = (const float*)d_in[32];
  const float* tb2      = (const float*)d_in[33];
  const float* out_w    = (const float*)d_in[34];
  const float* out_b    = (const float*)d_in[35];

  float* ws = (float*)d_ws;
  ushort_t* Ah   = (ushort_t*)ws;
  ushort_t* Al   = (ushort_t*)(ws + AL_OFF);
  ushort_t* Bh   = (ushort_t*)(ws + B_OFF);
  ushort_t* Bl   = (ushort_t*)(ws + BL_OFF);
  ushort_t* Cb16 = (ushort_t*)ws;
  ushort_t* Bb16 = (ushort_t*)(ws + B_OFF);
  ushort_t* A16  = (ushort_t*)ws;
  float* C      = ws + C_OFF;
  float* Dq     = ws + D_OFF;
  float* E      = ws + E_OFF;
  float* Q      = ws + Q_OFF;
  float* cbT    = ws + CBT_OFF;
  float* cnorm  = ws + CNORM_OFF;
  float* counts = ws + COUNTS_OFF;
  float* sumsq  = ws + SUMSQ_OFF;

  size_t o = WT_OFF;
  float* wt_enc0  = ws + o; o += (size_t)3 * 16 * 64;
  float* wt_er0w1 = ws + o; o += (size_t)256 * 9 * 64;
  float* wt_er0w2 = ws + o; o += (size_t)64 * 256;
  float* wt_er1w1 = ws + o; o += (size_t)256 * 9 * 64;
  float* wt_er1w2 = ws + o; o += (size_t)64 * 256;
  float* wt_eadj  = ws + o; o += (size_t)256 * 64;
  float* wt_dadj  = ws + o; o += (size_t)64 * 256;
  float* wt_dr0w1 = ws + o; o += (size_t)256 * 9 * 64;
  float* wt_dr0w2 = ws + o; o += (size_t)64 * 256;
  float* wt_dr1w1 = ws + o; o += (size_t)256 * 9 * 64;
  float* wt_dr1w2 = ws + o; o += (size_t)64 * 256;
  // bf16 tconv weights (FIXED sizes: u16count/2 floats)
  ushort_t* wbT0 = (ushort_t*)(ws + o); o += 262144;  // 4*128*256*4 u16 = 524288
  ushort_t* wbT1 = (ushort_t*)(ws + o); o += 65536;   // 4*64*128*4  u16 = 131072
  ushort_t* wbT2 = (ushort_t*)(ws + o); o += 16384;   // 4*32*64*4   u16 = 32768
  // split encoder conv weights ([co][ci][16] layout)
  ushort_t* wsh1 = (ushort_t*)(ws + o); o += 65536;   // 128*64*16 u16
  ushort_t* wsl1 = (ushort_t*)(ws + o); o += 65536;
  ushort_t* wsh2 = (ushort_t*)(ws + o); o += 262144;  // 256*128*16 u16
  ushort_t* wsl2 = (ushort_t*)(ws + o); o += 262144;

  float* fout = (float*)d_out;

  #define GB(n) (((n) + 255) / 256)
  hipMemsetAsync(ws, 0, WT_OFF * sizeof(float), stream);

  k_wt_conv<<<GB(3 * 64 * 16), 256, 0, stream>>>(enc_w0, wt_enc0, 3, 64, 16);
  k_wt_conv<<<GB(256 * 64 * 9), 256, 0, stream>>>(er0w1, wt_er0w1, 256, 64, 9);
  k_wt_conv<<<GB(64 * 256), 256, 0, stream>>>(er0w2, wt_er0w2, 64, 256, 1);
  k_wt_conv<<<GB(256 * 64 * 9), 256, 0, stream>>>(er1w1, wt_er1w1, 256, 64, 9);
  k_wt_conv<<<GB(64 * 256), 256, 0, stream>>>(er1w2, wt_er1w2, 64, 256, 1);
  k_wt_conv<<<GB(256 * 64), 256, 0, stream>>>(eadj_w, wt_eadj, 256, 64, 1);
  k_wt_conv<<<GB(64 * 256), 256, 0, stream>>>(dadj_w, wt_dadj, 64, 256, 1);
  k_wt_conv<<<GB(256 * 64 * 9), 256, 0, stream>>>(dr0w1, wt_dr0w1, 256, 64, 9);
  k_wt_conv<<<GB(64 * 256), 256, 0, stream>>>(dr0w2, wt_dr0w2, 64, 256, 1);
  k_wt_conv<<<GB(256 * 64 * 9), 256, 0, stream>>>(dr1w1, wt_dr1w1, 256, 64, 9);
  k_wt_conv<<<GB(64 * 256), 256, 0, stream>>>(dr1w2, wt_dr1w2, 64, 256, 1);
  k_wtb<<<GB(524288), 256, 0, stream>>>(tw0, wbT0, 256, 128);
  k_wtb<<<GB(131072), 256, 0, stream>>>(tw1, wbT1, 128, 64);
  k_wtb<<<GB(32768), 256, 0, stream>>>(tw2, wbT2, 64, 32);
  k_wsplit<<<GB(131072), 256, 0, stream>>>(enc_w1, wsh1, wsl1, 131072);
  k_wsplit<<<GB(524288), 256, 0, stream>>>(enc_w2, wsh2, wsl2, 524288);
  k_cbt<<<4, 256, 0, stream>>>(codebook, cbT, cnorm);

  // ---------- encoder ----------
  k_conv4s2_s3<<<dim3(16, 4, 32), 256, 0, stream>>>(x, wt_enc0, enc_b0, Ah, Al);
  k_conv4s2_mfma<6, 64, 128, 130, 16900, 66, 4356, 1>
      <<<dim3(64, 2, 32), 256, 0, stream>>>(Ah, Al, wsh1, wsl1, enc_b1, nullptr, Bh, Bl);
  hipMemsetAsync(ws, 0, (size_t)18939904 * sizeof(float), stream);  // C+Dq halos (A dead)
  k_conv4s2_mfma<5, 128, 256, 66, 4356, 34, 1156, 0>
      <<<dim3(16, 4, 32), 256, 0, stream>>>(Bh, Bl, wsh2, wsl2, enc_b2, C, nullptr, nullptr);
  k_conv3x3_px<<<dim3(4, 4, 32), 256, 0, stream>>>(C, wt_er0w1, er0b1, E);
  k_conv1x1_px<1, 1, 0, 1, 0><<<dim3(4, 16, 32), 256, 0, stream>>>(E, wt_er0w2, er0b2, C, Dq, 64, 256);
  k_conv3x3_px<<<dim3(4, 4, 32), 256, 0, stream>>>(Dq, wt_er1w1, er1b1, E);
  k_conv1x1_px<1, 1, 0, 1, 0><<<dim3(4, 16, 32), 256, 0, stream>>>(E, wt_er1w2, er1b2, Dq, C, 64, 256);
  k_conv1x1_px<0, 0, 1, 0, 0><<<dim3(4, 4, 32), 256, 0, stream>>>(C, wt_eadj, eadj_b, nullptr, E, 256, 64);
  // ---------- VQ ----------
  k_vq<<<2048, 256, 0, stream>>>(E, cbT, cnorm, codebook, Q, counts, sumsq);
  // ---------- decoder ----------
  k_conv1x1_px<0, 0, 0, 1, 0><<<dim3(4, 16, 32), 256, 0, stream>>>(Q, wt_dadj, dadj_b, nullptr, C, 64, 256);
  k_conv3x3_px<<<dim3(4, 4, 32), 256, 0, stream>>>(C, wt_dr0w1, dr0b1, E);
  k_conv1x1_px<1, 1, 0, 1, 0><<<dim3(4, 16, 32), 256, 0, stream>>>(E, wt_dr0w2, dr0b2, C, Dq, 64, 256);
  k_conv3x3_px<<<dim3(4, 4, 32), 256, 0, stream>>>(Dq, wt_dr1w1, dr1b1, E);
  hipMemsetAsync(ws, 0, (size_t)4734976 * sizeof(float), stream);   // Cb16 halos (fp32 C dead)
  k_conv1x1_px<1, 1, 0, 1, 1><<<dim3(4, 16, 32), 256, 0, stream>>>(E, wt_dr1w2, dr1b2, Dq, (float*)Cb16, 64, 256);
  hipMemsetAsync(ws + B_OFF, 0, (size_t)8921088 * sizeof(float), stream);  // Bb16 halos
  k_tconv_mfma<64, 64, 5, 256, 128, 34, 1156, 66, 4356, 0, 4>
      <<<dim3(16, 8, 32), 256, 0, stream>>>(Cb16, wbT0, tb0, nullptr, nullptr, Bb16, nullptr);
  hipMemsetAsync(ws, 0, (size_t)17305600 * sizeof(float), stream);  // A16 halos (Cb16 dead)
  k_tconv_mfma<64, 64, 6, 128, 64, 66, 4356, 130, 16900, 0, 4>
      <<<dim3(64, 4, 32), 256, 0, stream>>>(Bb16, wbT1, tb1, nullptr, nullptr, A16, nullptr);
  k_tconv_mfma<128, 32, 7, 64, 32, 130, 16900, 0, 0, 1, 2>
      <<<dim3(128, 4, 32), 256, 0, stream>>>(A16, wbT2, tb2, out_w, out_b, nullptr, fout);
  k_final<<<1, 256, 0, stream>>>(counts, sumsq, fout + 6291456);
  #undef GB
}